// Round 2
// baseline (653.835 us; speedup 1.0000x reference)
//
#include <hip/hip_runtime.h>

// AttnPool3D: logits = feat·w + 2*clip(mask,0,1); w = softmax_n(logits); out[b,c] = Σ_n feat*w
// Shapes fixed by setup_inputs(): B=2, C=128, D*H*W = N = 442368, all fp32.
constexpr int C   = 128;
constexpr int N   = 48 * 96 * 96;   // 442368
constexpr int B   = 2;
constexpr int NPB = 256;            // positions per block
constexpr int BPB = N / NPB;        // 1728 blocks per batch (exact)
constexpr int REC = 132;            // per-block record: [m, l, pad, pad, S[0..127]]
constexpr int CPT = 64;             // channels per thread (block = 512 threads, 2 ch-groups)

// One DPP reduce step: x += dpp_move(x). old=0 so masked-off rows add 0.
template <int CTRL, int RM>
__device__ __forceinline__ float dpp_add_step(float x) {
    int y = __builtin_amdgcn_update_dpp(0, __float_as_int(x), CTRL, RM, 0xF, true);
    return x + __int_as_float(y);
}

// Full 64-lane sum; result valid in lane 63. All VALU (DPP) — keeps the DS
// pipe free (64 of these per wave; ds_bpermute-based __shfl would bottleneck).
__device__ __forceinline__ float wave_sum64(float x) {
    x = dpp_add_step<0xB1, 0xF>(x);   // quad_perm [1,0,3,2]  (xor 1)
    x = dpp_add_step<0x4E, 0xF>(x);   // quad_perm [2,3,0,1]  (xor 2)
    x = dpp_add_step<0x141, 0xF>(x);  // row_half_mirror      (xor within 8)
    x = dpp_add_step<0x140, 0xF>(x);  // row_mirror           (xor within 16)
    x = dpp_add_step<0x142, 0xA>(x);  // row_bcast15 -> rows 1,3
    x = dpp_add_step<0x143, 0xC>(x);  // row_bcast31 -> rows 2,3
    return x;
}

// 512 threads: thread = (ch_group, position). f[64] per thread (~90 VGPR,
// fits the 128-VGPR cap of (512,4) with margin -> no scratch spill, 16 waves/CU).
__global__ __launch_bounds__(512, 4) void attn_pool_pass1(
    const float* __restrict__ feat, const float* __restrict__ mask,
    const float* __restrict__ w, float* __restrict__ rec)
{
    const int tid   = threadIdx.x;
    const int nidx  = tid & (NPB - 1);   // position within block tile
    const int cgrp  = tid >> 8;          // 0 or 1
    const int cbase = cgrp * CPT;
    const int blk   = blockIdx.x;
    const int b     = blk / BPB;
    const int n     = (blk % BPB) * NPB + nidx;

    const float* fp = feat + (size_t)b * C * N + (size_t)cbase * N + n;

    __shared__ float plog[2][NPB];
    __shared__ float rmax[8];
    __shared__ float rsum[8];
    __shared__ float SRed[8][CPT];

    // Load this thread's 64 channels once into VGPRs; partial logit on the fly.
    float f[CPT];
    float partial = 0.f;
#pragma unroll
    for (int c = 0; c < CPT; ++c) {
        f[c] = fp[(size_t)c * N];          // coalesced: lanes read consecutive n
        partial = fmaf(f[c], w[cbase + c], partial);
    }
    if (cgrp == 0) {
        float mv = mask[(size_t)b * N + n];
        mv = fminf(fmaxf(mv, 0.f), 1.f);
        partial += 2.0f * mv;
    }
    plog[cgrp][nidx] = partial;
    __syncthreads();

    const float logit = plog[0][nidx] + plog[1][nidx];
    const int lane = tid & 63;
    const int wv   = tid >> 6;           // 8 waves

    // block max of logits (values duplicated across ch-groups; max unaffected)
    float m = logit;
#pragma unroll
    for (int off = 32; off; off >>= 1) m = fmaxf(m, __shfl_xor(m, off, 64));
    if (lane == 0) rmax[wv] = m;
    __syncthreads();
    m = fmaxf(fmaxf(fmaxf(rmax[0], rmax[1]), fmaxf(rmax[2], rmax[3])),
              fmaxf(fmaxf(rmax[4], rmax[5]), fmaxf(rmax[6], rmax[7])));

    const float p = __expf(logit - m);

    // block sum of p: only ch-group 0 waves (0..3) contribute (avoid dup count)
    float l = p;
#pragma unroll
    for (int off = 32; off; off >>= 1) l += __shfl_xor(l, off, 64);
    if (lane == 0) rsum[wv] = l;

    // per-channel weighted partials: wave wv covers positions (wv&3)*64..+64
    // for channels cbase..cbase+63. DPP reduce over the wave's 64 positions.
    const bool lastlane = (lane == 63);
#pragma unroll
    for (int c = 0; c < CPT; ++c) {
        float v = wave_sum64(f[c] * p);
        if (lastlane) SRed[wv][c] = v;
    }
    __syncthreads();

    float* out = rec + (size_t)blk * REC;
    if (tid < C) {
        const int c = tid & (CPT - 1);
        const int g = (tid >> 6) * 4;    // 0 for c<64, 4 for c>=64
        out[4 + tid] = SRed[g][c] + SRed[g + 1][c] + SRed[g + 2][c] + SRed[g + 3][c];
    } else if (tid == C) {
        out[0] = m;
        out[1] = rsum[0] + rsum[1] + rsum[2] + rsum[3];
    }
}

__global__ __launch_bounds__(256) void attn_pool_pass2(
    const float* __restrict__ rec, float* __restrict__ out)
{
    const int b    = blockIdx.x;
    const int tid  = threadIdx.x;
    const int lane = tid & 63;
    const int wv   = tid >> 6;
    const float* base = rec + (size_t)b * BPB * REC;

    __shared__ float sc[BPB];   // per-block rescale factors e^{m_blk - M}
    __shared__ float r4[4];
    __shared__ float racc[C];

    // global max M over block maxima
    float m = -3.4e38f;
    for (int i = tid; i < BPB; i += 256) m = fmaxf(m, base[(size_t)i * REC]);
#pragma unroll
    for (int off = 32; off; off >>= 1) m = fmaxf(m, __shfl_xor(m, off, 64));
    if (lane == 0) r4[wv] = m;
    __syncthreads();
    const float M = fmaxf(fmaxf(r4[0], r4[1]), fmaxf(r4[2], r4[3]));
    __syncthreads();  // r4 reused for Z below

    // Z = sum_blk l_blk * e^{m_blk - M}; cache scales in LDS
    float z = 0.f;
    for (int i = tid; i < BPB; i += 256) {
        float e = __expf(base[(size_t)i * REC] - M);
        sc[i] = e;
        z = fmaf(base[(size_t)i * REC + 1], e, z);
    }
#pragma unroll
    for (int off = 32; off; off >>= 1) z += __shfl_xor(z, off, 64);
    if (lane == 0) r4[wv] = z;
    __syncthreads();
    const float Z = r4[0] + r4[1] + r4[2] + r4[3];

    // out[b,c] = (sum_blk S_blk[c] * e^{m_blk - M}) / Z ; 2 threads per channel
    const int c    = tid & (C - 1);
    const int half = tid >> 7;
    float acc = 0.f;
    const int i0 = half * (BPB / 2), i1 = i0 + (BPB / 2);
    for (int i = i0; i < i1; ++i)
        acc = fmaf(base[(size_t)i * REC + 4 + c], sc[i], acc);
    if (half == 1) racc[c] = acc;
    __syncthreads();
    if (half == 0) out[b * C + c] = (acc + racc[c]) / Z;
}

extern "C" void kernel_launch(void* const* d_in, const int* in_sizes, int n_in,
                              void* d_out, int out_size, void* d_ws, size_t ws_size,
                              hipStream_t stream)
{
    const float* feat = (const float*)d_in[0];
    const float* mask = (const float*)d_in[1];
    const float* w    = (const float*)d_in[2];
    float* rec = (float*)d_ws;   // needs B*BPB*REC*4 = ~1.83 MB of scratch

    attn_pool_pass1<<<B * BPB, 512, 0, stream>>>(feat, mask, w, rec);
    attn_pool_pass2<<<B, 256, 0, stream>>>(rec, (float*)d_out);
}

// Round 3
// 589.557 us; speedup vs baseline: 1.1090x; 1.1090x over previous
//
#include <hip/hip_runtime.h>

// AttnPool3D: logits = feat·w + 2*clip(mask,0,1); w = softmax_n(logits); out[b,c] = Σ_n feat*w
// Shapes fixed by setup_inputs(): B=2, C=128, N = 48*96*96 = 442368, all fp32.
//
// Single-read schedule: pass1 reads feat ONCE (453 MB) computing per-tile
// {max, sum, weighted channel sums}; pass2 combines 1728 tile records per batch.
// Measured context: harness restore+poison ≈ 560 µs fixed; our kernels ~100 µs.
constexpr int C   = 128;
constexpr int N   = 48 * 96 * 96;   // 442368
constexpr int B   = 2;
constexpr int P   = 256;            // positions per block tile
constexpr int BPB = N / P;          // 1728 (exact)
constexpr int G   = 16;             // channels per thread
constexpr int NW  = 8;              // waves per pass1 block (= channel groups)

// One DPP reduce step: x += dpp_move(x). old=0 so masked-off rows add 0.
template <int CTRL, int RM>
__device__ __forceinline__ float dpp_add_step(float x) {
    int y = __builtin_amdgcn_update_dpp(0, __float_as_int(x), CTRL, RM, 0xF, true);
    return x + __int_as_float(y);
}
// Full 64-lane sum; result valid in lane 63. All VALU (DPP), DS pipe stays free.
__device__ __forceinline__ float wave_sum64(float x) {
    x = dpp_add_step<0xB1, 0xF>(x);   // xor 1
    x = dpp_add_step<0x4E, 0xF>(x);   // xor 2
    x = dpp_add_step<0x141, 0xF>(x);  // row_half_mirror (xor 4)
    x = dpp_add_step<0x140, 0xF>(x);  // row_mirror (xor 8)
    x = dpp_add_step<0x142, 0xA>(x);  // row_bcast15 -> rows 1,3
    x = dpp_add_step<0x143, 0xC>(x);  // row_bcast31 -> rows 2,3
    return x;
}

// 512 threads = 8 waves. Wave w owns channels [16w,16w+16) for ALL 256 positions
// of the tile; thread t owns positions 4t..4t+3 (float4 loads: 1 KB per wave
// per load instruction — coalescing sweet spot). f4[16] = 64 VGPRs data.
__global__ __launch_bounds__(512, 4) void attn_pool_pass1(
    const float* __restrict__ feat, const float* __restrict__ mask,
    const float* __restrict__ w, float* __restrict__ Sout, float* __restrict__ ml)
{
    const int tid = threadIdx.x;
    const int wv  = tid >> 6;          // wave = channel group, 0..7
    const int t   = tid & 63;          // position-quad within tile
    const int blk = blockIdx.x;
    const int b   = blk / BPB;
    const int n0  = (blk % BPB) * P;
    const int cb  = wv * G;

    const float* fbase = feat + (size_t)b * C * N + n0 + 4 * t;

    __shared__ float4 plog[NW][64];    // per-group partial logits (8 KB)
    __shared__ float  rmax[NW];
    __shared__ float  rsum1;
    __shared__ float  SRed[NW][G];

    // Load 16 channels x 4 positions once; fold partial logit on the fly.
    float4 f[G];
    float4 pl = make_float4(0.f, 0.f, 0.f, 0.f);
#pragma unroll
    for (int c = 0; c < G; ++c) {
        f[c] = *reinterpret_cast<const float4*>(fbase + (size_t)(cb + c) * N);
        const float wc = w[cb + c];    // wave-uniform -> scalar load
        pl.x = fmaf(f[c].x, wc, pl.x);
        pl.y = fmaf(f[c].y, wc, pl.y);
        pl.z = fmaf(f[c].z, wc, pl.z);
        pl.w = fmaf(f[c].w, wc, pl.w);
    }
    if (wv == 0) {  // fold mask bias into group-0 partial (sums to full logit)
        float4 mv = *reinterpret_cast<const float4*>(mask + (size_t)b * N + n0 + 4 * t);
        pl.x += 2.f * fminf(fmaxf(mv.x, 0.f), 1.f);
        pl.y += 2.f * fminf(fmaxf(mv.y, 0.f), 1.f);
        pl.z += 2.f * fminf(fmaxf(mv.z, 0.f), 1.f);
        pl.w += 2.f * fminf(fmaxf(mv.w, 0.f), 1.f);
    }
    plog[wv][t] = pl;
    __syncthreads();

    // full logits for this thread's 4 positions = sum of the 8 group partials
    float4 lg = plog[0][t];
#pragma unroll
    for (int g = 1; g < NW; ++g) {
        float4 q = plog[g][t];
        lg.x += q.x; lg.y += q.y; lg.z += q.z; lg.w += q.w;
    }

    // tile max (duplicated across waves; max unaffected)
    float m = fmaxf(fmaxf(lg.x, lg.y), fmaxf(lg.z, lg.w));
#pragma unroll
    for (int off = 32; off; off >>= 1) m = fmaxf(m, __shfl_xor(m, off, 64));
    if (t == 0) rmax[wv] = m;
    __syncthreads();
    m = fmaxf(fmaxf(fmaxf(rmax[0], rmax[1]), fmaxf(rmax[2], rmax[3])),
              fmaxf(fmaxf(rmax[4], rmax[5]), fmaxf(rmax[6], rmax[7])));

    const float p0 = __expf(lg.x - m), p1 = __expf(lg.y - m);
    const float p2 = __expf(lg.z - m), p3 = __expf(lg.w - m);

    // tile sum of p: wave 0 covers all 256 positions exactly once
    if (wv == 0) {
        float l = ((p0 + p1) + (p2 + p3));
#pragma unroll
        for (int off = 32; off; off >>= 1) l += __shfl_xor(l, off, 64);
        if (t == 0) rsum1 = l;
    }

    // S_c = sum over the wave's 256 positions of f*p  (16 DPP chains/thread)
#pragma unroll
    for (int c = 0; c < G; ++c) {
        float s = f[c].x * p0;
        s = fmaf(f[c].y, p1, s);
        s = fmaf(f[c].z, p2, s);
        s = fmaf(f[c].w, p3, s);
        s = wave_sum64(s);
        if (t == 63) SRed[wv][c] = s;
    }
    __syncthreads();

    if (tid < C) {
        Sout[(size_t)blk * C + tid] = SRed[tid >> 4][tid & 15];  // contiguous record
    } else if (tid == C) {
        ml[2 * blk]     = m;
        ml[2 * blk + 1] = rsum1;
    }
}

// One 1024-thread block per batch. Phase A: M and Z from the compact ml array
// (13.8 KB contiguous). Phase B: 8 chunks x 128 channels, fully coalesced
// reads of S[i][c] (512 B per record per chunk), LDS combine, divide by Z.
__global__ __launch_bounds__(1024) void attn_pool_pass2(
    const float* __restrict__ S, const float* __restrict__ ml,
    float* __restrict__ out)
{
    const int b    = blockIdx.x;
    const int tid  = threadIdx.x;
    const int lane = tid & 63;
    const int wv   = tid >> 6;          // 0..15
    const float* mlb = ml + (size_t)b * BPB * 2;
    const float* Sb  = S  + (size_t)b * BPB * C;

    __shared__ float sc[BPB];           // e^{m_i - M}  (6.9 KB)
    __shared__ float redA[16], redB[16];
    __shared__ float racc[8][C];        // chunk partials (4 KB)

    // global max M over tile maxima
    float m = -3.4e38f;
    for (int i = tid; i < BPB; i += 1024) m = fmaxf(m, mlb[2 * i]);
#pragma unroll
    for (int off = 32; off; off >>= 1) m = fmaxf(m, __shfl_xor(m, off, 64));
    if (lane == 0) redA[wv] = m;
    __syncthreads();
    float M = redA[0];
#pragma unroll
    for (int k = 1; k < 16; ++k) M = fmaxf(M, redA[k]);

    // Z = sum_i l_i * e^{m_i - M}; cache scales in LDS
    float z = 0.f;
    for (int i = tid; i < BPB; i += 1024) {
        float e = __expf(mlb[2 * i] - M);
        sc[i] = e;
        z = fmaf(mlb[2 * i + 1], e, z);
    }
#pragma unroll
    for (int off = 32; off; off >>= 1) z += __shfl_xor(z, off, 64);
    if (lane == 0) redB[wv] = z;
    __syncthreads();
    float Z = redB[0];
#pragma unroll
    for (int k = 1; k < 16; ++k) Z += redB[k];

    // chunked weighted combine of S records (coalesced: lanes -> consecutive c)
    const int c  = tid & (C - 1);
    const int ck = tid >> 7;            // 0..7
    const int i0 = ck * (BPB / 8), i1 = i0 + (BPB / 8);
    float acc = 0.f;
    for (int i = i0; i < i1; ++i)
        acc = fmaf(Sb[(size_t)i * C + c], sc[i], acc);
    racc[ck][c] = acc;
    __syncthreads();

    if (tid < C) {
        float tot = 0.f;
#pragma unroll
        for (int k = 0; k < 8; ++k) tot += racc[k][tid];
        out[b * C + tid] = tot / Z;
    }
}

extern "C" void kernel_launch(void* const* d_in, const int* in_sizes, int n_in,
                              void* d_out, int out_size, void* d_ws, size_t ws_size,
                              hipStream_t stream)
{
    const float* feat = (const float*)d_in[0];
    const float* mask = (const float*)d_in[1];
    const float* w    = (const float*)d_in[2];

    float* Sout = (float*)d_ws;                         // B*BPB*C floats = 1.77 MB
    float* ml   = Sout + (size_t)B * BPB * C;           // B*BPB*2 floats = 27.6 KB

    attn_pool_pass1<<<B * BPB, 512, 0, stream>>>(feat, mask, w, Sout, ml);
    attn_pool_pass2<<<B, 1024, 0, stream>>>(Sout, ml, (float*)d_out);
}